// Round 16
// baseline (121.655 us; speedup 1.0000x reference)
//
#include <hip/hip_runtime.h>

#define IN_F 1024
#define OUT_F 1024
#define NNZ 16384

typedef _Float16 f16;
typedef _Float16 f16x4 __attribute__((ext_vector_type(4)));
typedef _Float16 f16x8 __attribute__((ext_vector_type(8)));
typedef float f32x4 __attribute__((ext_vector_type(4)));
typedef unsigned short ushort8 __attribute__((ext_vector_type(8)));

#define AS1 __attribute__((address_space(1)))
#define AS3 __attribute__((address_space(3)))

// ---------------------------------------------------------------------------
// Workspace: Wl = LINEAR W_eff (f16, 2 MiB) @0; Xs (LINEAR f16 X) @2MiB+4096.
// Swizzle lives in the DMA source address (m173): lane slot u: r=u>>3, bb=u&7
// reads block (bb^(r&7)) of row r; LDS dest linear; ds_read applies same XOR.
// SYNC INVARIANT (r9): DMA-staged LDS is written by ALL waves; vmcnt drains
// only the issuing wave's loads -> VMW(n) -> s_barrier before cross-wave read.
// SCHEDULING (r16): intra-tile order is NOT pinned -- fragment reads are
// compiler-visible loads; hipcc emits counted lgkmcnt per MFMA (m97). Only
// the VMW->barrier gate and post-barrier hoist-guard are pinned.
// ---------------------------------------------------------------------------

__device__ __forceinline__ int compute_mode(const unsigned short* __restrict__ w,
                                            float* smax, int* semax) {
  int t = threadIdx.x;
  const float* wf = (const float*)w;
  float m32 = fmaxf(fabsf(wf[t]), fabsf(wf[t + 256]));
  int e8 = 0;
#pragma unroll
  for (int j = 0; j < 8; ++j) {
    unsigned short u = w[t * 8 + j];
    int e = (u >> 7) & 0xFF;
    e8 = e > e8 ? e : e8;
  }
  smax[t] = m32; semax[t] = e8;
  __syncthreads();
  for (int s = 128; s > 0; s >>= 1) {
    if (t < s) {
      smax[t] = fmaxf(smax[t], smax[t + s]);
      semax[t] = semax[t] > semax[t + s] ? semax[t] : semax[t + s];
    }
    __syncthreads();
  }
  int m;
  if (!(smax[0] > 1e-6f)) m = 2;
  else if (semax[0] >= 140) m = 0;
  else m = 1;
  return m;
}

__device__ __forceinline__ float load_w(const void* base, size_t i, int mode) {
  if (mode == 0) return ((const float*)base)[i];
  if (mode == 1) {
    unsigned int u = (unsigned int)((const unsigned short*)base)[i] << 16;
    return __uint_as_float(u);
  }
  return (float)((const f16*)base)[i];
}

__global__ void prep_base(const void* __restrict__ base, f16* __restrict__ Wl) {
  __shared__ float smax[256];
  __shared__ int semax[256];
  int mode = compute_mode((const unsigned short*)base, smax, semax);
  int id = blockIdx.x * 256 + threadIdx.x;
  size_t off = (size_t)id * 8;
  f16x8 h;
  if (mode == 0) {
    const float* b = (const float*)base + off;
    float4 v0 = *reinterpret_cast<const float4*>(b);
    float4 v1 = *reinterpret_cast<const float4*>(b + 4);
    h = (f16x8){(f16)v0.x, (f16)v0.y, (f16)v0.z, (f16)v0.w,
                (f16)v1.x, (f16)v1.y, (f16)v1.z, (f16)v1.w};
  } else if (mode == 1) {
    ushort8 uv = *reinterpret_cast<const ushort8*>((const unsigned short*)base + off);
#pragma unroll
    for (int j = 0; j < 8; ++j)
      h[j] = (f16)__uint_as_float((unsigned int)uv[j] << 16);
  } else {
    h = *reinterpret_cast<const f16x8*>((const f16*)base + off);
  }
  *reinterpret_cast<f16x8*>(Wl + off) = h;
}

__global__ void prep_scatter(const void* __restrict__ base,
                             const void* __restrict__ vals,
                             const int* __restrict__ idx,
                             const float* __restrict__ alpha,
                             f16* __restrict__ Wl) {
  __shared__ float smax[256];
  __shared__ int semax[256];
  int mode = compute_mode((const unsigned short*)base, smax, semax);
  int i = blockIdx.x * 256 + threadIdx.x;
  if (i >= NNZ) return;
  int id = idx[i];
  float v = load_w(base, id, mode) + alpha[0] * load_w(vals, i, mode);
  Wl[id] = (f16)v;
}

// conv_x v5: pure linear cvt copy -- both sides perfectly coalesced.
__global__ void __launch_bounds__(256) conv_x(const float* __restrict__ X,
                                              f16* __restrict__ Xs, int total) {
  int stride = gridDim.x * 256;
  for (int id = blockIdx.x * 256 + threadIdx.x; id < total; id += stride) {
    size_t off = (size_t)id * 8;
    const float* p = X + off;
    float4 v0 = *reinterpret_cast<const float4*>(p);
    float4 v1 = *reinterpret_cast<const float4*>(p + 4);
    f16x8 h = {(f16)v0.x, (f16)v0.y, (f16)v0.z, (f16)v0.w,
               (f16)v1.x, (f16)v1.y, (f16)v1.z, (f16)v1.w};
    *reinterpret_cast<f16x8*>(Xs + off) = h;
  }
}

#define SB0 __builtin_amdgcn_sched_barrier(0)
#define VMW(N) asm volatile("s_waitcnt vmcnt(" #N ")" ::: "memory")

// ---------------------------------------------------------------------------
// gemm12: gemm11's single-barrier skeleton (replay-proven r15), intra-tile
// scheduling FREED. 256x256, BK=64, 512 thr (8 waves 2Mx4N), wave tile
// 128x64. LDS 160 KiB: A triple-buffered (3x32 KiB), B double (2x32 KiB).
// Tile KT body (no internal fences): {ds_read S0 frags; issue QB(KT+1);
// 32 MFMA(S0); ds_read S1 frags; issue QA(KT+2); 32 MFMA(S1)} -- compiler
// interleaves reads<->MFMAs with counted lgkmcnt. Gate: VMW(4) (drains
// A/B(KT+1), keeps QA(KT+2)) -> s_barrier -> SB0 (hoist guard).
// WAR safety: every ds_read is consumed by an MFMA before the barrier, so
// reads are drained pre-barrier by the compiler's counted waits.
// ---------------------------------------------------------------------------

#define ISSUE_QA11(QI, KT1, AP)                                                \
    __builtin_amdgcn_global_load_lds(                                          \
        (const AS1 void*)(Xs + rowOffA[QI] + (KT1) * 64 + swzc),               \
        (AS3 void*)(&sA[((AP) * 4 + (QI)) * 4096 + t * 8]), 16, 0, 0)

#define ISSUE_QB11(QI, KT1, BP)                                                \
    __builtin_amdgcn_global_load_lds(                                          \
        (const AS1 void*)(Wl + rowOffB[QI] + (KT1) * 64 + swzc),               \
        (AS3 void*)(&sB[((BP) * 4 + (QI)) * 4096 + t * 8]), 16, 0, 0)

#define DSREAD11(AP, BP, S_) do {                                              \
    _Pragma("unroll")                                                          \
    for (int qq_ = 0; qq_ < 2; ++qq_) {                                        \
      int qa_ = ((AP) * 4 + wm * 2 + qq_) * 4096;                              \
      _Pragma("unroll")                                                        \
      for (int mf_ = 0; mf_ < 4; ++mf_) {                                      \
        int r_ = mf_ * 16 + lr;                                                \
        int blk_ = ((S_) * 4 + lk) ^ (lr & 7);                                 \
        afr[qq_][mf_] = *reinterpret_cast<const f16x8*>(&sA[qa_ + r_ * 64 + blk_ * 8]); \
      }                                                                        \
    }                                                                          \
    int qb_ = ((BP) * 4 + wn) * 4096;                                          \
    _Pragma("unroll")                                                          \
    for (int nf_ = 0; nf_ < 4; ++nf_) {                                        \
      int r_ = nf_ * 16 + lr;                                                  \
      int blk_ = ((S_) * 4 + lk) ^ (lr & 7);                                   \
      bfr[nf_] = *reinterpret_cast<const f16x8*>(&sB[qb_ + r_ * 64 + blk_ * 8]); \
    }                                                                          \
  } while (0)

// MFMA cluster WITHOUT forced lgkm(0)/SB0: compiler emits counted waits.
#define MFMA32_FREE do {                                                       \
    __builtin_amdgcn_s_setprio(1);                                             \
    _Pragma("unroll")                                                          \
    for (int qq_ = 0; qq_ < 2; ++qq_)                                          \
      _Pragma("unroll")                                                        \
      for (int mf_ = 0; mf_ < 4; ++mf_)                                        \
        _Pragma("unroll")                                                      \
        for (int nf_ = 0; nf_ < 4; ++nf_)                                      \
          acc[qq_ * 4 + mf_][nf_] = __builtin_amdgcn_mfma_f32_16x16x32_f16(    \
              afr[qq_][mf_], bfr[nf_], acc[qq_ * 4 + mf_][nf_], 0, 0, 0);      \
    __builtin_amdgcn_s_setprio(0);                                             \
  } while (0)

#define KTILE12(AP, BP, KT, ISSB, ISSA, VMN, LASTBAR) do {                     \
    DSREAD11(AP, BP, 0);                                                       \
    if (ISSB) {                                                                \
      ISSUE_QB11(0, (KT) + 1, ((KT) + 1) & 1); ISSUE_QB11(1, (KT) + 1, ((KT) + 1) & 1); \
      ISSUE_QB11(2, (KT) + 1, ((KT) + 1) & 1); ISSUE_QB11(3, (KT) + 1, ((KT) + 1) & 1); } \
    MFMA32_FREE;                                                               \
    DSREAD11(AP, BP, 1);                                                       \
    if (ISSA) {                                                                \
      ISSUE_QA11(0, (KT) + 2, ((KT) + 2) % 3); ISSUE_QA11(1, (KT) + 2, ((KT) + 2) % 3); \
      ISSUE_QA11(2, (KT) + 2, ((KT) + 2) % 3); ISSUE_QA11(3, (KT) + 2, ((KT) + 2) % 3); } \
    MFMA32_FREE;                                                               \
    if (LASTBAR) {                                                             \
      VMW(VMN);                                                                \
      __builtin_amdgcn_s_barrier();  /* WAR(this) + RAW(next), r9 */           \
      SB0;                           /* hoist guard for next tile's reads */   \
    }                                                                          \
  } while (0)

__global__ void __launch_bounds__(512, 2) gemm12(const f16* __restrict__ Xs,
                                                 const f16* __restrict__ Wl,
                                                 float* __restrict__ C) {
  extern __shared__ f16 lds[];
  f16* sA = lds;              // 3 bufs x [4 quarters][4096] = 96 KiB
  f16* sB = lds + 49152;      // 2 bufs x [4 quarters][4096] = 64 KiB

  int bidx = blockIdx.x;
  int q = gridDim.x >> 3;
  int wg = (bidx & 7) * q + (bidx >> 3);
  int mt = wg >> 2, nt = wg & 3;

  int t = threadIdx.x;
  int lane = t & 63;
  int w = t >> 6;
  int wm = w >> 2;
  int wn = w & 3;
  int lr = lane & 15;
  int lk = lane >> 4;

  int rS = t >> 3;
  int swzc = (((t & 7) ^ (rS & 7)) << 3);
  size_t rowOffA[4], rowOffB[4];
#pragma unroll
  for (int qi = 0; qi < 4; ++qi) {
    rowOffA[qi] = (size_t)(mt * 256 + qi * 64 + rS) * IN_F;
    rowOffB[qi] = (size_t)(nt * 256 + qi * 64 + rS) * IN_F;
  }

  f16x8 afr[2][4], bfr[4];
  f32x4 acc[8][4];
#pragma unroll
  for (int i = 0; i < 8; ++i)
#pragma unroll
    for (int j = 0; j < 4; ++j)
      acc[i][j] = (f32x4){0.f, 0.f, 0.f, 0.f};

  // prologue: QA(0)->A0, QB(0)->B0, QA(1)->A1; VMW(4); barrier (r9).
  ISSUE_QA11(0, 0, 0); ISSUE_QA11(1, 0, 0); ISSUE_QA11(2, 0, 0); ISSUE_QA11(3, 0, 0);
  ISSUE_QB11(0, 0, 0); ISSUE_QB11(1, 0, 0); ISSUE_QB11(2, 0, 0); ISSUE_QB11(3, 0, 0);
  ISSUE_QA11(0, 1, 1); ISSUE_QA11(1, 1, 1); ISSUE_QA11(2, 1, 1); ISSUE_QA11(3, 1, 1);
  VMW(4);
  __builtin_amdgcn_s_barrier();
  SB0;

  KTILE12(0, 0,  0, true,  true,  4, true);
  KTILE12(1, 1,  1, true,  true,  4, true);
  KTILE12(2, 0,  2, true,  true,  4, true);
  KTILE12(0, 1,  3, true,  true,  4, true);
  KTILE12(1, 0,  4, true,  true,  4, true);
  KTILE12(2, 1,  5, true,  true,  4, true);
  KTILE12(0, 0,  6, true,  true,  4, true);
  KTILE12(1, 1,  7, true,  true,  4, true);
  KTILE12(2, 0,  8, true,  true,  4, true);
  KTILE12(0, 1,  9, true,  true,  4, true);
  KTILE12(1, 0, 10, true,  true,  4, true);
  KTILE12(2, 1, 11, true,  true,  4, true);
  KTILE12(0, 0, 12, true,  true,  4, true);
  KTILE12(1, 1, 13, true,  true,  4, true);
  KTILE12(2, 0, 14, true,  false, 0, true);
  KTILE12(0, 1, 15, false, false, 0, false);

  float* Cw = C + (size_t)(mt * 256 + wm * 128 + lk * 4) * OUT_F + nt * 256 + wn * 64 + lr;
#pragma unroll
  for (int m = 0; m < 8; ++m) {
    int rowo = (m >> 2) * 64 + (m & 3) * 16;
#pragma unroll
    for (int nf = 0; nf < 4; ++nf)
#pragma unroll
      for (int g = 0; g < 4; ++g)
        Cw[(size_t)(rowo + g) * OUT_F + nf * 16] = acc[m][nf][g];
  }
}

// ---------------------------------------------------------------------------
// gemm11 fallback (replay-proven r15, ~71 us): pinned-schedule variant,
// used if 160 KiB attribute fails (defensive; r15 proved it succeeds).
// ---------------------------------------------------------------------------

#define MFMA32_PIN do {                                                        \
    asm volatile("s_waitcnt lgkmcnt(0)" ::: "memory");                         \
    SB0;                                                                       \
    __builtin_amdgcn_s_setprio(1);                                             \
    _Pragma("unroll")                                                          \
    for (int qq_ = 0; qq_ < 2; ++qq_)                                          \
      _Pragma("unroll")                                                        \
      for (int mf_ = 0; mf_ < 4; ++mf_)                                        \
        _Pragma("unroll")                                                      \
        for (int nf_ = 0; nf_ < 4; ++nf_)                                      \
          acc[qq_ * 4 + mf_][nf_] = __builtin_amdgcn_mfma_f32_16x16x32_f16(    \
              afr[qq_][mf_], bfr[nf_], acc[qq_ * 4 + mf_][nf_], 0, 0, 0);      \
    __builtin_amdgcn_s_setprio(0);                                             \
  } while (0)

#define KTILE11(AP, BP, KT, ISSB, ISSA, VMN, LASTBAR) do {                     \
    DSREAD11(AP, BP, 0);                                                       \
    if (ISSB) { SB0;                                                           \
      ISSUE_QB11(0, (KT) + 1, ((KT) + 1) & 1); ISSUE_QB11(1, (KT) + 1, ((KT) + 1) & 1); \
      ISSUE_QB11(2, (KT) + 1, ((KT) + 1) & 1); ISSUE_QB11(3, (KT) + 1, ((KT) + 1) & 1); } \
    MFMA32_PIN;                                                                \
    DSREAD11(AP, BP, 1);                                                       \
    if (ISSA) { SB0;                                                           \
      ISSUE_QA11(0, (KT) + 2, ((KT) + 2) % 3); ISSUE_QA11(1, (KT) + 2, ((KT) + 2) % 3); \
      ISSUE_QA11(2, (KT) + 2, ((KT) + 2) % 3); ISSUE_QA11(3, (KT) + 2, ((KT) + 2) % 3); } \
    MFMA32_PIN;                                                                \
    if (LASTBAR) {                                                             \
      SB0; VMW(VMN); SB0;                                                      \
      __builtin_amdgcn_s_barrier();                                            \
      SB0;                                                                     \
    }                                                                          \
  } while (0)

__global__ void __launch_bounds__(512, 2) gemm11(const f16* __restrict__ Xs,
                                                 const f16* __restrict__ Wl,
                                                 float* __restrict__ C) {
  extern __shared__ f16 lds[];
  f16* sA = lds;
  f16* sB = lds + 49152;

  int bidx = blockIdx.x;
  int q = gridDim.x >> 3;
  int wg = (bidx & 7) * q + (bidx >> 3);
  int mt = wg >> 2, nt = wg & 3;

  int t = threadIdx.x;
  int lane = t & 63;
  int w = t >> 6;
  int wm = w >> 2;
  int wn = w & 3;
  int lr = lane & 15;
  int lk = lane >> 4;

  int rS = t >> 3;
  int swzc = (((t & 7) ^ (rS & 7)) << 3);
  size_t rowOffA[4], rowOffB[4];
#pragma unroll
  for (int qi = 0; qi < 4; ++qi) {
    rowOffA[qi] = (size_t)(mt * 256 + qi * 64 + rS) * IN_F;
    rowOffB[qi] = (size_t)(nt * 256 + qi * 64 + rS) * IN_F;
  }

  f16x8 afr[2][4], bfr[4];
  f32x4 acc[8][4];
#pragma unroll
  for (int i = 0; i < 8; ++i)
#pragma unroll
    for (int j = 0; j < 4; ++j)
      acc[i][j] = (f32x4){0.f, 0.f, 0.f, 0.f};

  ISSUE_QA11(0, 0, 0); ISSUE_QA11(1, 0, 0); ISSUE_QA11(2, 0, 0); ISSUE_QA11(3, 0, 0);
  ISSUE_QB11(0, 0, 0); ISSUE_QB11(1, 0, 0); ISSUE_QB11(2, 0, 0); ISSUE_QB11(3, 0, 0);
  ISSUE_QA11(0, 1, 1); ISSUE_QA11(1, 1, 1); ISSUE_QA11(2, 1, 1); ISSUE_QA11(3, 1, 1);
  SB0; VMW(4); SB0;
  __builtin_amdgcn_s_barrier();
  SB0;

  KTILE11(0, 0,  0, true,  true,  4, true);
  KTILE11(1, 1,  1, true,  true,  4, true);
  KTILE11(2, 0,  2, true,  true,  4, true);
  KTILE11(0, 1,  3, true,  true,  4, true);
  KTILE11(1, 0,  4, true,  true,  4, true);
  KTILE11(2, 1,  5, true,  true,  4, true);
  KTILE11(0, 0,  6, true,  true,  4, true);
  KTILE11(1, 1,  7, true,  true,  4, true);
  KTILE11(2, 0,  8, true,  true,  4, true);
  KTILE11(0, 1,  9, true,  true,  4, true);
  KTILE11(1, 0, 10, true,  true,  4, true);
  KTILE11(2, 1, 11, true,  true,  4, true);
  KTILE11(0, 0, 12, true,  true,  4, true);
  KTILE11(1, 1, 13, true,  true,  4, true);
  KTILE11(2, 0, 14, true,  false, 0, true);
  KTILE11(0, 1, 15, false, false, 0, false);

  float* Cw = C + (size_t)(mt * 256 + wm * 128 + lk * 4) * OUT_F + nt * 256 + wn * 64 + lr;
#pragma unroll
  for (int m = 0; m < 8; ++m) {
    int rowo = (m >> 2) * 64 + (m & 3) * 16;
#pragma unroll
    for (int nf = 0; nf < 4; ++nf)
#pragma unroll
      for (int g = 0; g < 4; ++g)
        Cw[(size_t)(rowo + g) * OUT_F + nf * 16] = acc[m][nf][g];
  }
}

extern "C" void kernel_launch(void* const* d_in, const int* in_sizes, int n_in,
                              void* d_out, int out_size, void* d_ws, size_t ws_size,
                              hipStream_t stream) {
  const float* X = (const float*)d_in[0];
  const void* base = d_in[1];
  const void* vals = d_in[2];
  const int* idx = (const int*)d_in[3];
  const float* alpha = (const float*)d_in[4];
  float* out = (float*)d_out;
  f16* Wl = (f16*)d_ws;                                   // linear W_eff
  f16* Xs = (f16*)((char*)d_ws + 2 * 1024 * 1024 + 4096); // linear f16 X

  int M = in_sizes[0] / IN_F;              // 32768
  int total = (M * IN_F) / 8;              // 8-f16 chunks

  prep_base<<<dim3(512), dim3(256), 0, stream>>>(base, Wl);
  prep_scatter<<<dim3((NNZ + 255) / 256), dim3(256), 0, stream>>>(base, vals, idx, alpha, Wl);
  conv_x<<<dim3(2048), dim3(256), 0, stream>>>(X, Xs, total);

  hipError_t e = hipFuncSetAttribute(reinterpret_cast<const void*>(&gemm12),
                                     hipFuncAttributeMaxDynamicSharedMemorySize, 163840);
  if (e == hipSuccess) {
    gemm12<<<dim3((M / 256) * 4), dim3(512), 163840, stream>>>(Xs, Wl, out);
  } else {
    (void)hipFuncSetAttribute(reinterpret_cast<const void*>(&gemm11),
                              hipFuncAttributeMaxDynamicSharedMemorySize, 163840);
    gemm11<<<dim3((M / 256) * 4), dim3(512), 163840, stream>>>(Xs, Wl, out);
  }
}

// Round 17
// 119.113 us; speedup vs baseline: 1.0213x; 1.0213x over previous
//
#include <hip/hip_runtime.h>

#define IN_F 1024
#define OUT_F 1024
#define NNZ 16384

typedef _Float16 f16;
typedef _Float16 f16x8 __attribute__((ext_vector_type(8)));
typedef float f32x4 __attribute__((ext_vector_type(4)));
typedef unsigned short ushort8 __attribute__((ext_vector_type(8)));

#define AS1 __attribute__((address_space(1)))
#define AS3 __attribute__((address_space(3)))

// ---------------------------------------------------------------------------
// Workspace: Wl = LINEAR W_eff (f16, 2 MiB) @0; Xs (LINEAR f16 X) @2MiB+4096.
// Swizzle lives in the DMA source address (m173): lane slot u: r=u>>3, bb=u&7
// reads block (bb^(r&7)) of row r; LDS dest linear; ds_read applies same XOR.
// SYNC INVARIANT (r9): DMA-staged LDS is written by ALL waves; vmcnt drains
// only the issuing wave's loads -> VMW(n) -> s_barrier before cross-wave read.
// r17: 2 blocks/CU (80 KiB LDS) -- co-resident blocks overlap each other's
// barrier stalls (m114 mechanism, excluded since r5's 128 KiB tiles).
// ---------------------------------------------------------------------------

__device__ __forceinline__ int compute_mode(const unsigned short* __restrict__ w,
                                            float* smax, int* semax) {
  int t = threadIdx.x;
  const float* wf = (const float*)w;
  float m32 = fmaxf(fabsf(wf[t]), fabsf(wf[t + 256]));
  int e8 = 0;
#pragma unroll
  for (int j = 0; j < 8; ++j) {
    unsigned short u = w[t * 8 + j];
    int e = (u >> 7) & 0xFF;
    e8 = e > e8 ? e : e8;
  }
  smax[t] = m32; semax[t] = e8;
  __syncthreads();
  for (int s = 128; s > 0; s >>= 1) {
    if (t < s) {
      smax[t] = fmaxf(smax[t], smax[t + s]);
      semax[t] = semax[t] > semax[t + s] ? semax[t] : semax[t + s];
    }
    __syncthreads();
  }
  int m;
  if (!(smax[0] > 1e-6f)) m = 2;        // native f16
  else if (semax[0] >= 140) m = 0;      // f32-upcast
  else m = 1;                           // bf16
  return m;
}

__device__ __forceinline__ float load_w(const void* base, size_t i, int mode) {
  if (mode == 0) return ((const float*)base)[i];
  if (mode == 1) {
    unsigned int u = (unsigned int)((const unsigned short*)base)[i] << 16;
    return __uint_as_float(u);
  }
  return (float)((const f16*)base)[i];
}

__global__ void prep_base(const void* __restrict__ base, f16* __restrict__ Wl) {
  __shared__ float smax[256];
  __shared__ int semax[256];
  int mode = compute_mode((const unsigned short*)base, smax, semax);
  int id = blockIdx.x * 256 + threadIdx.x;
  size_t off = (size_t)id * 8;
  f16x8 h;
  if (mode == 0) {
    const float* b = (const float*)base + off;
    float4 v0 = *reinterpret_cast<const float4*>(b);
    float4 v1 = *reinterpret_cast<const float4*>(b + 4);
    h = (f16x8){(f16)v0.x, (f16)v0.y, (f16)v0.z, (f16)v0.w,
                (f16)v1.x, (f16)v1.y, (f16)v1.z, (f16)v1.w};
  } else if (mode == 1) {
    ushort8 uv = *reinterpret_cast<const ushort8*>((const unsigned short*)base + off);
#pragma unroll
    for (int j = 0; j < 8; ++j)
      h[j] = (f16)__uint_as_float((unsigned int)uv[j] << 16);
  } else {
    h = *reinterpret_cast<const f16x8*>((const f16*)base + off);
  }
  *reinterpret_cast<f16x8*>(Wl + off) = h;
}

// conv_x v6: linear cvt copy + fused scatter (blocks < 64; NNZ = 64*256).
// Runs after prep_base on the stream, so the scatter's WAW on Wl is ordered.
__global__ void __launch_bounds__(256) conv_x(const float* __restrict__ X,
                                              f16* __restrict__ Xs, int total,
                                              const void* __restrict__ base,
                                              const void* __restrict__ vals,
                                              const int* __restrict__ idx,
                                              const float* __restrict__ alpha,
                                              f16* __restrict__ Wl) {
  __shared__ float smax[256];
  __shared__ int semax[256];
  if (blockIdx.x < 64) {
    int mode = compute_mode((const unsigned short*)base, smax, semax);
    int i = blockIdx.x * 256 + threadIdx.x;   // i < 16384 = NNZ
    int id = idx[i];
    float v = load_w(base, id, mode) + alpha[0] * load_w(vals, i, mode);
    Wl[id] = (f16)v;
  }
  int stride = gridDim.x * 256;
  for (int id = blockIdx.x * 256 + threadIdx.x; id < total; id += stride) {
    size_t off = (size_t)id * 8;
    const float* p = X + off;
    float4 v0 = *reinterpret_cast<const float4*>(p);
    float4 v1 = *reinterpret_cast<const float4*>(p + 4);
    f16x8 h = {(f16)v0.x, (f16)v0.y, (f16)v0.z, (f16)v0.w,
               (f16)v1.x, (f16)v1.y, (f16)v1.z, (f16)v1.w};
    *reinterpret_cast<f16x8*>(Xs + off) = h;
  }
}

#define SB0 __builtin_amdgcn_sched_barrier(0)
#define VMW(N) asm volatile("s_waitcnt vmcnt(" #N ")" ::: "memory")

// ---------------------------------------------------------------------------
// gemm13: gemm12's single-barrier triple-A pipeline at HALF tile for
// 2 blocks/CU. BM=BN=128, BK=64, 256 thr (4 waves 2Mx2N), wave tile 64x64.
// LDS 80 KiB: A 3 bufs x [2 quarters][4096] (48 KiB), B 2 bufs x same (32 KiB).
// Tile KT body (schedule free): {ds_read S0; issue QB(KT+1)->B[(KT+1)&1];
// 32 MFMA; ds_read S1; issue QA(KT+2)->A[(KT+2)%3]; 32 MFMA} ->
// VMW(4) (queue [A(KT+1):4, B(KT+1):4, A(KT+2):4] -> drains 8, keeps 4) ->
// s_barrier (WAR+RAW, r9) -> SB0. VMW(0) only prologue / KT=14.
// ---------------------------------------------------------------------------

#define ISSUE_QA13(QI, KT1, AP) do {                                           \
    __builtin_amdgcn_global_load_lds(                                          \
        (const AS1 void*)(Xs + rowOffA[QI][0] + (KT1) * 64 + swzc),            \
        (AS3 void*)(&sA[((AP) * 2 + (QI)) * 4096 + t * 8]), 16, 0, 0);         \
    __builtin_amdgcn_global_load_lds(                                          \
        (const AS1 void*)(Xs + rowOffA[QI][1] + (KT1) * 64 + swzc),            \
        (AS3 void*)(&sA[((AP) * 2 + (QI)) * 4096 + t * 8 + 2048]), 16, 0, 0);  \
  } while (0)

#define ISSUE_QB13(QI, KT1, BP) do {                                           \
    __builtin_amdgcn_global_load_lds(                                          \
        (const AS1 void*)(Wl + rowOffB[QI][0] + (KT1) * 64 + swzc),            \
        (AS3 void*)(&sB[((BP) * 2 + (QI)) * 4096 + t * 8]), 16, 0, 0);         \
    __builtin_amdgcn_global_load_lds(                                          \
        (const AS1 void*)(Wl + rowOffB[QI][1] + (KT1) * 64 + swzc),            \
        (AS3 void*)(&sB[((BP) * 2 + (QI)) * 4096 + t * 8 + 2048]), 16, 0, 0);  \
  } while (0)

#define DSREAD13(AP, BP, S_) do {                                              \
    int qa_ = ((AP) * 2 + wm) * 4096;                                          \
    _Pragma("unroll")                                                          \
    for (int mf_ = 0; mf_ < 4; ++mf_) {                                        \
      int r_ = mf_ * 16 + lr;                                                  \
      int blk_ = ((S_) * 4 + lk) ^ (lr & 7);                                   \
      afr[mf_] = *reinterpret_cast<const f16x8*>(&sA[qa_ + r_ * 64 + blk_ * 8]); \
    }                                                                          \
    int qb_ = ((BP) * 2 + wn) * 4096;                                          \
    _Pragma("unroll")                                                          \
    for (int nf_ = 0; nf_ < 4; ++nf_) {                                        \
      int r_ = nf_ * 16 + lr;                                                  \
      int blk_ = ((S_) * 4 + lk) ^ (lr & 7);                                   \
      bfr[nf_] = *reinterpret_cast<const f16x8*>(&sB[qb_ + r_ * 64 + blk_ * 8]); \
    }                                                                          \
  } while (0)

#define MFMA16F do {                                                           \
    __builtin_amdgcn_s_setprio(1);                                             \
    _Pragma("unroll")                                                          \
    for (int mf_ = 0; mf_ < 4; ++mf_)                                          \
      _Pragma("unroll")                                                        \
      for (int nf_ = 0; nf_ < 4; ++nf_)                                        \
        acc[mf_][nf_] = __builtin_amdgcn_mfma_f32_16x16x32_f16(                \
            afr[mf_], bfr[nf_], acc[mf_][nf_], 0, 0, 0);                       \
    __builtin_amdgcn_s_setprio(0);                                             \
  } while (0)

#define KTILE13(AP, BP, KT, ISSB, ISSA, VMN, LASTBAR) do {                     \
    DSREAD13(AP, BP, 0);                                                       \
    if (ISSB) { ISSUE_QB13(0, (KT) + 1, ((KT) + 1) & 1);                       \
                ISSUE_QB13(1, (KT) + 1, ((KT) + 1) & 1); }                     \
    MFMA16F;                                                                   \
    DSREAD13(AP, BP, 1);                                                       \
    if (ISSA) { ISSUE_QA13(0, (KT) + 2, ((KT) + 2) % 3);                       \
                ISSUE_QA13(1, (KT) + 2, ((KT) + 2) % 3); }                     \
    MFMA16F;                                                                   \
    if (LASTBAR) {                                                             \
      VMW(VMN);                                                                \
      __builtin_amdgcn_s_barrier();  /* WAR(this) + RAW(next), r9 */           \
      SB0;                           /* hoist guard */                         \
    }                                                                          \
  } while (0)

__global__ void __launch_bounds__(256, 2) gemm13(const f16* __restrict__ Xs,
                                                 const f16* __restrict__ Wl,
                                                 float* __restrict__ C) {
  extern __shared__ f16 lds[];
  f16* sA = lds;              // 3 bufs x [2 quarters][4096] = 48 KiB
  f16* sB = lds + 24576;      // 2 bufs x [2 quarters][4096] = 32 KiB

  int bidx = blockIdx.x;
  int q = gridDim.x >> 3;     // 2048/8 = 256
  int wg = (bidx & 7) * q + (bidx >> 3);
  int mt = wg >> 3, nt = wg & 7;

  int t = threadIdx.x;
  int lane = t & 63;
  int w = t >> 6;
  int wm = w >> 1;            // M half (64 rows) == A quarter
  int wn = w & 1;             // N half (64 cols) == B quarter
  int lr = lane & 15;
  int lk = lane >> 4;

  int rS = t >> 3;            // 0..31
  int swzc = (((t & 7) ^ (rS & 7)) << 3);
  size_t rowOffA[2][2], rowOffB[2][2];
#pragma unroll
  for (int qi = 0; qi < 2; ++qi)
#pragma unroll
    for (int h = 0; h < 2; ++h) {
      rowOffA[qi][h] = (size_t)(mt * 128 + qi * 64 + h * 32 + rS) * IN_F;
      rowOffB[qi][h] = (size_t)(nt * 128 + qi * 64 + h * 32 + rS) * IN_F;
    }

  f16x8 afr[4], bfr[4];
  f32x4 acc[4][4];
#pragma unroll
  for (int i = 0; i < 4; ++i)
#pragma unroll
    for (int j = 0; j < 4; ++j)
      acc[i][j] = (f32x4){0.f, 0.f, 0.f, 0.f};

  // prologue: QA(0)->A0, QB(0)->B0, QA(1)->A1; VMW(4) keeps QA(1); barrier.
  ISSUE_QA13(0, 0, 0); ISSUE_QA13(1, 0, 0);
  ISSUE_QB13(0, 0, 0); ISSUE_QB13(1, 0, 0);
  ISSUE_QA13(0, 1, 1); ISSUE_QA13(1, 1, 1);
  VMW(4);
  __builtin_amdgcn_s_barrier();
  SB0;

  KTILE13(0, 0,  0, true,  true,  4, true);
  KTILE13(1, 1,  1, true,  true,  4, true);
  KTILE13(2, 0,  2, true,  true,  4, true);
  KTILE13(0, 1,  3, true,  true,  4, true);
  KTILE13(1, 0,  4, true,  true,  4, true);
  KTILE13(2, 1,  5, true,  true,  4, true);
  KTILE13(0, 0,  6, true,  true,  4, true);
  KTILE13(1, 1,  7, true,  true,  4, true);
  KTILE13(2, 0,  8, true,  true,  4, true);
  KTILE13(0, 1,  9, true,  true,  4, true);
  KTILE13(1, 0, 10, true,  true,  4, true);
  KTILE13(2, 1, 11, true,  true,  4, true);
  KTILE13(0, 0, 12, true,  true,  4, true);
  KTILE13(1, 1, 13, true,  true,  4, true);
  KTILE13(2, 0, 14, true,  false, 0, true);
  KTILE13(0, 1, 15, false, false, 0, false);

  // epilogue: D layout col = lane&15, row = (lane>>4)*4 + reg
  float* Cw = C + (size_t)(mt * 128 + wm * 64 + lk * 4) * OUT_F + nt * 128 + wn * 64 + lr;
#pragma unroll
  for (int mf = 0; mf < 4; ++mf)
#pragma unroll
    for (int nf = 0; nf < 4; ++nf)
#pragma unroll
      for (int g = 0; g < 4; ++g)
        Cw[(size_t)(mf * 16 + g) * OUT_F + nf * 16] = acc[mf][nf][g];
}

// ---------------------------------------------------------------------------
// gemm12 fallback (replay-proven r16, ~71-75 us): 256-tile single-barrier.
// ---------------------------------------------------------------------------

#define ISSUE_QA11(QI, KT1, AP)                                                \
    __builtin_amdgcn_global_load_lds(                                          \
        (const AS1 void*)(Xs + rowOffA[QI] + (KT1) * 64 + swzc),               \
        (AS3 void*)(&sA[((AP) * 4 + (QI)) * 4096 + t * 8]), 16, 0, 0)

#define ISSUE_QB11(QI, KT1, BP)                                                \
    __builtin_amdgcn_global_load_lds(                                          \
        (const AS1 void*)(Wl + rowOffB[QI] + (KT1) * 64 + swzc),               \
        (AS3 void*)(&sB[((BP) * 4 + (QI)) * 4096 + t * 8]), 16, 0, 0)

#define DSREAD11(AP, BP, S_) do {                                              \
    _Pragma("unroll")                                                          \
    for (int qq_ = 0; qq_ < 2; ++qq_) {                                        \
      int qa_ = ((AP) * 4 + wm * 2 + qq_) * 4096;                              \
      _Pragma("unroll")                                                        \
      for (int mf_ = 0; mf_ < 4; ++mf_) {                                      \
        int r_ = mf_ * 16 + lr;                                                \
        int blk_ = ((S_) * 4 + lk) ^ (lr & 7);                                 \
        afr[qq_][mf_] = *reinterpret_cast<const f16x8*>(&sA[qa_ + r_ * 64 + blk_ * 8]); \
      }                                                                        \
    }                                                                          \
    int qb_ = ((BP) * 4 + wn) * 4096;                                          \
    _Pragma("unroll")                                                          \
    for (int nf_ = 0; nf_ < 4; ++nf_) {                                        \
      int r_ = nf_ * 16 + lr;                                                  \
      int blk_ = ((S_) * 4 + lk) ^ (lr & 7);                                   \
      bfr[nf_] = *reinterpret_cast<const f16x8*>(&sB[qb_ + r_ * 64 + blk_ * 8]); \
    }                                                                          \
  } while (0)

#define MFMA32_FREE do {                                                       \
    __builtin_amdgcn_s_setprio(1);                                             \
    _Pragma("unroll")                                                          \
    for (int qq_ = 0; qq_ < 2; ++qq_)                                          \
      _Pragma("unroll")                                                        \
      for (int mf_ = 0; mf_ < 4; ++mf_)                                        \
        _Pragma("unroll")                                                      \
        for (int nf_ = 0; nf_ < 4; ++nf_)                                      \
          acc[qq_ * 4 + mf_][nf_] = __builtin_amdgcn_mfma_f32_16x16x32_f16(    \
              afr[qq_][mf_], bfr[nf_], acc[qq_ * 4 + mf_][nf_], 0, 0, 0);      \
    __builtin_amdgcn_s_setprio(0);                                             \
  } while (0)

#define KTILE12(AP, BP, KT, ISSB, ISSA, VMN, LASTBAR) do {                     \
    DSREAD11(AP, BP, 0);                                                       \
    if (ISSB) {                                                                \
      ISSUE_QB11(0, (KT) + 1, ((KT) + 1) & 1); ISSUE_QB11(1, (KT) + 1, ((KT) + 1) & 1); \
      ISSUE_QB11(2, (KT) + 1, ((KT) + 1) & 1); ISSUE_QB11(3, (KT) + 1, ((KT) + 1) & 1); } \
    MFMA32_FREE;                                                               \
    DSREAD11(AP, BP, 1);                                                       \
    if (ISSA) {                                                                \
      ISSUE_QA11(0, (KT) + 2, ((KT) + 2) % 3); ISSUE_QA11(1, (KT) + 2, ((KT) + 2) % 3); \
      ISSUE_QA11(2, (KT) + 2, ((KT) + 2) % 3); ISSUE_QA11(3, (KT) + 2, ((KT) + 2) % 3); } \
    MFMA32_FREE;                                                               \
    if (LASTBAR) {                                                             \
      VMW(VMN);                                                                \
      __builtin_amdgcn_s_barrier();                                            \
      SB0;                                                                     \
    }                                                                          \
  } while (0)

__global__ void __launch_bounds__(512, 2) gemm12(const f16* __restrict__ Xs,
                                                 const f16* __restrict__ Wl,
                                                 float* __restrict__ C) {
  extern __shared__ f16 lds[];
  f16* sA = lds;
  f16* sB = lds + 49152;

  int bidx = blockIdx.x;
  int q = gridDim.x >> 3;
  int wg = (bidx & 7) * q + (bidx >> 3);
  int mt = wg >> 2, nt = wg & 3;

  int t = threadIdx.x;
  int lane = t & 63;
  int w = t >> 6;
  int wm = w >> 2;
  int wn = w & 3;
  int lr = lane & 15;
  int lk = lane >> 4;

  int rS = t >> 3;
  int swzc = (((t & 7) ^ (rS & 7)) << 3);
  size_t rowOffA[4], rowOffB[4];
#pragma unroll
  for (int qi = 0; qi < 4; ++qi) {
    rowOffA[qi] = (size_t)(mt * 256 + qi * 64 + rS) * IN_F;
    rowOffB[qi] = (size_t)(nt * 256 + qi * 64 + rS) * IN_F;
  }

  f16x8 afr[2][4], bfr[4];
  f32x4 acc[8][4];
#pragma unroll
  for (int i = 0; i < 8; ++i)
#pragma unroll
    for (int j = 0; j < 4; ++j)
      acc[i][j] = (f32x4){0.f, 0.f, 0.f, 0.f};

  ISSUE_QA11(0, 0, 0); ISSUE_QA11(1, 0, 0); ISSUE_QA11(2, 0, 0); ISSUE_QA11(3, 0, 0);
  ISSUE_QB11(0, 0, 0); ISSUE_QB11(1, 0, 0); ISSUE_QB11(2, 0, 0); ISSUE_QB11(3, 0, 0);
  ISSUE_QA11(0, 1, 1); ISSUE_QA11(1, 1, 1); ISSUE_QA11(2, 1, 1); ISSUE_QA11(3, 1, 1);
  VMW(4);
  __builtin_amdgcn_s_barrier();
  SB0;

  KTILE12(0, 0,  0, true,  true,  4, true);
  KTILE12(1, 1,  1, true,  true,  4, true);
  KTILE12(2, 0,  2, true,  true,  4, true);
  KTILE12(0, 1,  3, true,  true,  4, true);
  KTILE12(1, 0,  4, true,  true,  4, true);
  KTILE12(2, 1,  5, true,  true,  4, true);
  KTILE12(0, 0,  6, true,  true,  4, true);
  KTILE12(1, 1,  7, true,  true,  4, true);
  KTILE12(2, 0,  8, true,  true,  4, true);
  KTILE12(0, 1,  9, true,  true,  4, true);
  KTILE12(1, 0, 10, true,  true,  4, true);
  KTILE12(2, 1, 11, true,  true,  4, true);
  KTILE12(0, 0, 12, true,  true,  4, true);
  KTILE12(1, 1, 13, true,  true,  4, true);
  KTILE12(2, 0, 14, true,  false, 0, true);
  KTILE12(0, 1, 15, false, false, 0, false);

  float* Cw = C + (size_t)(mt * 256 + wm * 128 + lk * 4) * OUT_F + nt * 256 + wn * 64 + lr;
#pragma unroll
  for (int m = 0; m < 8; ++m) {
    int rowo = (m >> 2) * 64 + (m & 3) * 16;
#pragma unroll
    for (int nf = 0; nf < 4; ++nf)
#pragma unroll
      for (int g = 0; g < 4; ++g)
        Cw[(size_t)(rowo + g) * OUT_F + nf * 16] = acc[m][nf][g];
  }
}

extern "C" void kernel_launch(void* const* d_in, const int* in_sizes, int n_in,
                              void* d_out, int out_size, void* d_ws, size_t ws_size,
                              hipStream_t stream) {
  const float* X = (const float*)d_in[0];
  const void* base = d_in[1];
  const void* vals = d_in[2];
  const int* idx = (const int*)d_in[3];
  const float* alpha = (const float*)d_in[4];
  float* out = (float*)d_out;
  f16* Wl = (f16*)d_ws;                                   // linear W_eff
  f16* Xs = (f16*)((char*)d_ws + 2 * 1024 * 1024 + 4096); // linear f16 X

  int M = in_sizes[0] / IN_F;              // 32768
  int total = (M * IN_F) / 8;              // 8-f16 chunks

  prep_base<<<dim3(512), dim3(256), 0, stream>>>(base, Wl);
  conv_x<<<dim3(2048), dim3(256), 0, stream>>>(X, Xs, total, base, vals, idx, alpha, Wl);

  hipError_t e = hipFuncSetAttribute(reinterpret_cast<const void*>(&gemm13),
                                     hipFuncAttributeMaxDynamicSharedMemorySize, 81920);
  if (e == hipSuccess) {
    gemm13<<<dim3((M / 128) * 8), dim3(256), 81920, stream>>>(Xs, Wl, out);
  } else {
    (void)hipFuncSetAttribute(reinterpret_cast<const void*>(&gemm12),
                              hipFuncAttributeMaxDynamicSharedMemorySize, 163840);
    gemm12<<<dim3((M / 256) * 4), dim3(512), 163840, stream>>>(Xs, Wl, out);
  }
}